// Round 5
// baseline (527.458 us; speedup 1.0000x reference)
//
#include <hip/hip_runtime.h>

#define SLEN 2048
#define BATCH 32
#define HDIM 512
#define KDIM 1024   // 2H

typedef _Float16 f16x8 __attribute__((ext_vector_type(8)));
typedef _Float16 f16x4 __attribute__((ext_vector_type(4)));
typedef float f32x4 __attribute__((ext_vector_type(4)));

__device__ __forceinline__ float fast_tanh(float x) {
  float e = __expf(2.0f * x);
  return 1.0f - 2.0f * __builtin_amdgcn_rcpf(e + 1.0f);
}

// ---- prep: [0,512) W2->f16 | [512,4608) s1 | [4608,4640) zero score ----
__global__ __launch_bounds__(256) void prep_k(const float* __restrict__ attn_w,
                                              const float* __restrict__ attn_b,
                                              const float* __restrict__ hidden,
                                              _Float16* __restrict__ Bt,
                                              float* __restrict__ s1,
                                              float* __restrict__ score) {
  if (blockIdx.x < 512) {
    int t = blockIdx.x * 256 + threadIdx.x;
    int h = t >> 8;
    int c = t & 255;
    float4 x = *(const float4*)(attn_w + (size_t)h * 2048 + 1024 + c * 4);
    f16x4 y = {(_Float16)x.x, (_Float16)x.y, (_Float16)x.z, (_Float16)x.w};
    *(f16x4*)(Bt + (size_t)h * 1024 + c * 4) = y;
  } else if (blockIdx.x < 4608) {
    int o = (blockIdx.x - 512) * 4 + (threadIdx.x >> 6);  // one wave per output
    int b = o >> 9, h = o & 511;
    int lane = threadIdx.x & 63;
    const float4* hp = (const float4*)(hidden + (size_t)b * 1024);
    const float4* wp = (const float4*)(attn_w + (size_t)h * 2048);
    float acc = 0.f;
#pragma unroll
    for (int c = 0; c < 4; ++c) {
      float4 a = hp[c * 64 + lane];
      float4 wv = wp[c * 64 + lane];
      acc += a.x * wv.x + a.y * wv.y + a.z * wv.z + a.w * wv.w;
    }
#pragma unroll
    for (int off = 1; off < 64; off <<= 1) acc += __shfl_xor(acc, off);
    if (lane == 0) s1[o] = acc + attn_b[h];
  } else {
    int idx = (blockIdx.x - 4608) * 256 + threadIdx.x;
    float4 z = {0.f, 0.f, 0.f, 0.f};
    ((float4*)score)[idx] = z;
    ((float4*)score)[idx + 8192] = z;
  }
}

// ---- Main fused GEMM: BARRIER-FREE K-loop ----
// Block = 512 threads = 8 waves stacked in m. Block tile 512m x 128n.
// B panel (128 x half-K=512, f16) staged in LDS ONCE per half (2 stages total);
// XOR-swizzled (phys 16B-chunk = chunk ^ (row&7)) -> 2-way on ds_read_b128.
// A streamed global->registers directly (no LDS, no barriers, no DMA):
// compiler emits counted per-register vmcnt waits; loads of step ks+1 fly
// under MFMA of step ks via #pragma unroll 2 pipelining.
// Grid 512 = 128 mt x 4 nt; XCD swizzle: 4 nt-siblings of an mt share an XCD
// (A panel fetched from HBM once, served by that XCD's L2 thereafter).
__global__ __launch_bounds__(512, 2) void gemm_k(const float* __restrict__ eo,
                                                 const _Float16* __restrict__ Bt,
                                                 const float* __restrict__ s1,
                                                 const float* __restrict__ v,
                                                 float* __restrict__ score) {
  __shared__ __align__(16) char smem[131072];   // B panel 128 rows x 1KB

  int bid = blockIdx.x;
  int x = bid & 7;
  int nt = (bid >> 3) & 3;
  int mt = (bid >> 5) * 8 + x;        // 0..127

  int tid = threadIdx.x;
  int lane = tid & 63;
  int w = tid >> 6;                   // 0..7
  int wm = w * 64;                    // wave m-offset within 512-row block tile
  int mrow = lane & 15;
  int quad = lane >> 4;
  int rk = mrow & 7;                  // bf row-swizzle key (same for all j)

  f32x4 acc[4][8];
#pragma unroll
  for (int i = 0; i < 4; ++i)
#pragma unroll
    for (int j = 0; j < 8; ++j) acc[i][j] = (f32x4){0.f, 0.f, 0.f, 0.f};

#pragma unroll 1
  for (int half = 0; half < 2; ++half) {
    int h0 = half * 512;

    // ---- stage B half-panel: 512 threads x 256 B, reg->swizzled ds_write ----
    __syncthreads();   // prior half's readers done (no-op cost on first pass)
    {
      int r = tid >> 2;                 // 0..127
      int cg = (tid & 3) * 16;          // 16-chunk group within the 64-chunk row
      const _Float16* src = Bt + (size_t)(nt * 128 + r) * 1024 + h0 + cg * 8;
      char* dst = smem + r * 1024;
#pragma unroll
      for (int c = 0; c < 16; ++c) {
        f16x8 vd = *(const f16x8*)(src + c * 8);
        int pc = (cg + c) ^ (r & 7);    // physical 16B chunk
        *(f16x8*)(dst + pc * 16) = vd;
      }
    }
    __syncthreads();

    // A fragment bases: frag i covers rows wm+16i+mrow, k = quad*8..+8 (+ks*32)
    const float* aB0 = eo + (size_t)(mt * 512 + wm + 0  + mrow) * 1024 + h0 + quad * 8;
    const float* aB1 = eo + (size_t)(mt * 512 + wm + 16 + mrow) * 1024 + h0 + quad * 8;
    const float* aB2 = eo + (size_t)(mt * 512 + wm + 32 + mrow) * 1024 + h0 + quad * 8;
    const float* aB3 = eo + (size_t)(mt * 512 + wm + 48 + mrow) * 1024 + h0 + quad * 8;

#pragma unroll 2
    for (int ks = 0; ks < 16; ++ks) {
      float4 ar0 = *(const float4*)(aB0 + ks * 32);
      float4 ar1 = *(const float4*)(aB0 + ks * 32 + 4);
      float4 ar2 = *(const float4*)(aB1 + ks * 32);
      float4 ar3 = *(const float4*)(aB1 + ks * 32 + 4);
      float4 ar4 = *(const float4*)(aB2 + ks * 32);
      float4 ar5 = *(const float4*)(aB2 + ks * 32 + 4);
      float4 ar6 = *(const float4*)(aB3 + ks * 32);
      float4 ar7 = *(const float4*)(aB3 + ks * 32 + 4);

      int cx = ((ks * 4 + quad) ^ rk) << 4;   // swizzled chunk byte offset
      f16x8 bf[8];
#pragma unroll
      for (int j = 0; j < 8; ++j)
        bf[j] = *(const f16x8*)(smem + ((16 * j + mrow) << 10) + cx);

      f16x8 af[4];
      af[0] = (f16x8){(_Float16)ar0.x, (_Float16)ar0.y, (_Float16)ar0.z, (_Float16)ar0.w,
                      (_Float16)ar1.x, (_Float16)ar1.y, (_Float16)ar1.z, (_Float16)ar1.w};
      af[1] = (f16x8){(_Float16)ar2.x, (_Float16)ar2.y, (_Float16)ar2.z, (_Float16)ar2.w,
                      (_Float16)ar3.x, (_Float16)ar3.y, (_Float16)ar3.z, (_Float16)ar3.w};
      af[2] = (f16x8){(_Float16)ar4.x, (_Float16)ar4.y, (_Float16)ar4.z, (_Float16)ar4.w,
                      (_Float16)ar5.x, (_Float16)ar5.y, (_Float16)ar5.z, (_Float16)ar5.w};
      af[3] = (f16x8){(_Float16)ar6.x, (_Float16)ar6.y, (_Float16)ar6.z, (_Float16)ar6.w,
                      (_Float16)ar7.x, (_Float16)ar7.y, (_Float16)ar7.z, (_Float16)ar7.w};

#pragma unroll
      for (int i = 0; i < 4; ++i)
#pragma unroll
        for (int j = 0; j < 8; ++j)
          acc[i][j] = __builtin_amdgcn_mfma_f32_16x16x32_f16(af[i], bf[j], acc[i][j], 0, 0, 0);
    }
  }

  // ---- Epilogue: energy = tanh(acc + s1[b][h]); score += energy * v[h] ----
  __syncthreads();
  float* s1s = (float*)smem;                 // [32][132] fp32 (stride-132)
  float* vsm = (float*)(smem + 16896);       // [128]
  for (int t = tid; t < 1024; t += 512) {
    int bb = t >> 5, cc = t & 31;
    ((float4*)s1s)[bb * 33 + cc] = *(const float4*)(s1 + (size_t)bb * 512 + nt * 128 + cc * 4);
  }
  if (tid < 32) ((float4*)vsm)[tid] = *(const float4*)(v + nt * 128 + tid * 4);
  __syncthreads();

  int lcol = mrow;
  float vv[8];
#pragma unroll
  for (int j = 0; j < 8; ++j) vv[j] = vsm[16 * j + lcol];

#pragma unroll
  for (int i = 0; i < 4; ++i) {
#pragma unroll
    for (int r = 0; r < 4; ++r) {
      int mloc = wm + 16 * i + 4 * quad + r;
      int bb = mloc & 31;   // mt*512 ≡ 0 (mod 32)
      float sum = 0.f;
#pragma unroll
      for (int j = 0; j < 8; ++j) {
        float e = acc[i][j][r] + s1s[bb * 132 + 16 * j + lcol];
        sum += fast_tanh(e) * vv[j];
      }
      sum += __shfl_xor(sum, 1);
      sum += __shfl_xor(sum, 2);
      sum += __shfl_xor(sum, 4);
      sum += __shfl_xor(sum, 8);
      if (lcol == 0) {
        int mg = mt * 512 + mloc;        // global row m = s*32 + b
        atomicAdd(&score[(mg & 31) * SLEN + (mg >> 5)], sum);
      }
    }
  }
}

// ---- Masked softmax over s for each b; score stored b-major [32][2048] ----
__global__ __launch_bounds__(256) void softmax_k(const float* __restrict__ score,
                                                 const int* __restrict__ mask,
                                                 float* __restrict__ out) {
  int b = blockIdx.x;
  int tid = threadIdx.x;
  int lane = tid & 63, w = tid >> 6;
  __shared__ float red[8];
  float vals[8];
  float mx = -3.4e38f;
#pragma unroll
  for (int i = 0; i < 8; ++i) {
    int s = i * 256 + tid;
    float xv = score[b * SLEN + s];
    if (mask[b * SLEN + s] == 0) xv = -1e10f;
    vals[i] = xv;
    mx = fmaxf(mx, xv);
  }
#pragma unroll
  for (int off = 1; off < 64; off <<= 1) mx = fmaxf(mx, __shfl_xor(mx, off));
  if (lane == 0) red[w] = mx;
  __syncthreads();
  mx = fmaxf(fmaxf(red[0], red[1]), fmaxf(red[2], red[3]));
  float sum = 0.f;
#pragma unroll
  for (int i = 0; i < 8; ++i) {
    vals[i] = __expf(vals[i] - mx);
    sum += vals[i];
  }
#pragma unroll
  for (int off = 1; off < 64; off <<= 1) sum += __shfl_xor(sum, off);
  if (lane == 0) red[4 + w] = sum;
  __syncthreads();
  sum = red[4] + red[5] + red[6] + red[7];
  float inv = 1.0f / sum;
#pragma unroll
  for (int i = 0; i < 8; ++i) out[b * SLEN + i * 256 + tid] = vals[i] * inv;
}

extern "C" void kernel_launch(void* const* d_in, const int* in_sizes, int n_in,
                              void* d_out, int out_size, void* d_ws, size_t ws_size,
                              hipStream_t stream) {
  const float* hidden = (const float*)d_in[0];
  const float* eo     = (const float*)d_in[1];
  const int*   mask   = (const int*)d_in[2];
  const float* attn_w = (const float*)d_in[3];
  const float* attn_b = (const float*)d_in[4];
  const float* v      = (const float*)d_in[5];
  float* out = (float*)d_out;

  char* wsb = (char*)d_ws;
  _Float16* Bt = (_Float16*)wsb;                              // 1 MB
  float* s1    = (float*)(wsb + (1 << 20));                   // 64 KB
  float* score = (float*)(wsb + (1 << 20) + (1 << 16));       // 256 KB

  prep_k<<<4640, 256, 0, stream>>>(attn_w, attn_b, hidden, Bt, s1, score);
  gemm_k<<<512, 512, 0, stream>>>(eo, Bt, s1, v, score);
  softmax_k<<<BATCH, 256, 0, stream>>>(score, mask, out);
}

// Round 6
// 496.744 us; speedup vs baseline: 1.0618x; 1.0618x over previous
//
#include <hip/hip_runtime.h>

#define SLEN 2048
#define BATCH 32
#define HDIM 512
#define KDIM 1024   // 2H

typedef _Float16 f16x8 __attribute__((ext_vector_type(8)));
typedef _Float16 f16x4 __attribute__((ext_vector_type(4)));
typedef float f32x4 __attribute__((ext_vector_type(4)));

__device__ __forceinline__ void gload16(const void* g, void* l) {
  __builtin_amdgcn_global_load_lds(
      (const __attribute__((address_space(1))) unsigned int*)g,
      (__attribute__((address_space(3))) unsigned int*)l, 16, 0, 0);
}

__device__ __forceinline__ float fast_tanh(float x) {
  float e = __expf(2.0f * x);
  return 1.0f - 2.0f * __builtin_amdgcn_rcpf(e + 1.0f);
}

// ---- prep: [0,512) W2->f16 | [512,4608) s1 ----  (no score zeroing needed)
__global__ __launch_bounds__(256) void prep_k(const float* __restrict__ attn_w,
                                              const float* __restrict__ attn_b,
                                              const float* __restrict__ hidden,
                                              _Float16* __restrict__ Bt,
                                              float* __restrict__ s1) {
  if (blockIdx.x < 512) {
    int t = blockIdx.x * 256 + threadIdx.x;
    int h = t >> 8;
    int c = t & 255;
    float4 x = *(const float4*)(attn_w + (size_t)h * 2048 + 1024 + c * 4);
    f16x4 y = {(_Float16)x.x, (_Float16)x.y, (_Float16)x.z, (_Float16)x.w};
    *(f16x4*)(Bt + (size_t)h * 1024 + c * 4) = y;
  } else {
    int o = (blockIdx.x - 512) * 4 + (threadIdx.x >> 6);  // one wave per output
    int b = o >> 9, h = o & 511;
    int lane = threadIdx.x & 63;
    const float4* hp = (const float4*)(hidden + (size_t)b * 1024);
    const float4* wp = (const float4*)(attn_w + (size_t)h * 2048);
    float acc = 0.f;
#pragma unroll
    for (int c = 0; c < 4; ++c) {
      float4 a = hp[c * 64 + lane];
      float4 wv = wp[c * 64 + lane];
      acc += a.x * wv.x + a.y * wv.y + a.z * wv.z + a.w * wv.w;
    }
#pragma unroll
    for (int off = 1; off < 64; off <<= 1) acc += __shfl_xor(acc, off);
    if (lane == 0) s1[o] = acc + attn_b[h];
  }
}

// ---- Main fused GEMM: BM=64, BN=512 (FULL N per block -> A read ONCE) ----
// 512 threads = 8 waves, each wave owns 64m x 64n (wn = w*64).
// A (fp32): full-line gload_lds DMA, source chunk-swizzled (phys c = logical
// c ^ (row&7)), double-buffered 2x8KB; read as float4-pairs + cvt to f16.
// B (f16, 1 MB, L2-resident per XCD): fragments loaded global->reg directly,
// issued BEFORE the next-tile DMA so compiler's counted per-reg vmcnt waits
// don't drain the prefetch.
// Epilogue: block owns all 512 h for its 64 rows -> cross-wave LDS reduce,
// plain stores to score (no atomics, no zero-init).
__global__ __launch_bounds__(512, 4) void gemm_k(const float* __restrict__ eo,
                                                 const _Float16* __restrict__ Bt,
                                                 const float* __restrict__ s1,
                                                 const float* __restrict__ v,
                                                 float* __restrict__ score) {
  constexpr int NKT = KDIM / 32;                 // 32 K-tiles of BK=32
  __shared__ __align__(16) char smem[16384];     // A: buf0 @0, buf1 @8192

  int mt = blockIdx.x;                 // 0..1023 ; rows mt*64..+64
  int tid = threadIdx.x;
  int lane = tid & 63;
  int w = tid >> 6;                    // 0..7
  int wn = w * 64;                     // wave n-offset (covers all 512 n)
  int mrow = lane & 15;
  int quad = lane >> 4;
  int rk = mrow & 7;                   // A row swizzle key

  // A DMA source: wave w stages rows 8w..8w+7; lane l writes dest chunk
  // (l&7) of row (l>>3) -> source logical chunk = (l&7) ^ (l>>3).
  const float* ga = eo + (size_t)(mt * 64 + 8 * w + (lane >> 3)) * KDIM
                       + ((lane & 7) ^ (lane >> 3)) * 4;

  // B fragment bases (per-lane): row wn+16j+mrow, k-slice quad*8 (+kt*32)
  const _Float16* bp0 = Bt + (size_t)(wn + 0  + mrow) * KDIM + quad * 8;
  const _Float16* bp1 = Bt + (size_t)(wn + 16 + mrow) * KDIM + quad * 8;
  const _Float16* bp2 = Bt + (size_t)(wn + 32 + mrow) * KDIM + quad * 8;
  const _Float16* bp3 = Bt + (size_t)(wn + 48 + mrow) * KDIM + quad * 8;

  f32x4 acc[4][4];
#pragma unroll
  for (int i = 0; i < 4; ++i)
#pragma unroll
    for (int j = 0; j < 4; ++j) acc[i][j] = (f32x4){0.f, 0.f, 0.f, 0.f};

  // ---- prologue: DMA tile 0 -> buf0, drain once ----
  gload16(ga, smem + w * 1024);
  ga += 32;
  __syncthreads();

#pragma unroll 1
  for (int kt = 0; kt < NKT; ++kt) {
    int cur = kt & 1;

    // B frags FIRST (older VMEM than the DMA -> waiting on them leaves the
    // DMA in flight under the compiler's counted vmcnt)
    f16x8 bf0 = *(const f16x8*)(bp0 + kt * 32);
    f16x8 bf1 = *(const f16x8*)(bp1 + kt * 32);
    f16x8 bf2 = *(const f16x8*)(bp2 + kt * 32);
    f16x8 bf3 = *(const f16x8*)(bp3 + kt * 32);

    if (kt + 1 < NKT) {                 // DMA next tile into the other buffer
      gload16(ga, smem + (cur ^ 1) * 8192 + w * 1024);
      ga += 32;
    }

    // A frags from LDS (fp32, swizzle-corrected) + cvt to f16
    const float* Ab = (const float*)(smem + cur * 8192);
    f16x8 af[4];
#pragma unroll
    for (int i = 0; i < 4; ++i) {
      const float* pa = Ab + (16 * i + mrow) * 32;
      float4 a0 = *(const float4*)(pa + (((2 * quad) ^ rk) << 2));
      float4 a1 = *(const float4*)(pa + (((2 * quad + 1) ^ rk) << 2));
      af[i] = (f16x8){(_Float16)a0.x, (_Float16)a0.y, (_Float16)a0.z, (_Float16)a0.w,
                      (_Float16)a1.x, (_Float16)a1.y, (_Float16)a1.z, (_Float16)a1.w};
    }

#pragma unroll
    for (int i = 0; i < 4; ++i) {
      acc[i][0] = __builtin_amdgcn_mfma_f32_16x16x32_f16(af[i], bf0, acc[i][0], 0, 0, 0);
      acc[i][1] = __builtin_amdgcn_mfma_f32_16x16x32_f16(af[i], bf1, acc[i][1], 0, 0, 0);
      acc[i][2] = __builtin_amdgcn_mfma_f32_16x16x32_f16(af[i], bf2, acc[i][2], 0, 0, 0);
      acc[i][3] = __builtin_amdgcn_mfma_f32_16x16x32_f16(af[i], bf3, acc[i][3], 0, 0, 0);
    }

    // end-of-iter barrier: next iter's readers of buf[cur^1] are gated on the
    // DMA via this barrier's implicit vmcnt drain (issued one full compute
    // phase earlier)
    __syncthreads();
  }

  // ---- Epilogue: energy = tanh(acc + s1[b][h]); partial = sum_h e*v[h] ----
  // Wave w covers h = wn..wn+64 only -> cross-wave reduce via LDS.
  float vv[4];
#pragma unroll
  for (int j = 0; j < 4; ++j) vv[j] = v[wn + 16 * j + mrow];

  float* part = (float*)smem;          // [8][64] partials (reuses A bufs)
#pragma unroll
  for (int i = 0; i < 4; ++i) {
#pragma unroll
    for (int r = 0; r < 4; ++r) {
      int mloc = 16 * i + 4 * quad + r;
      int b = mloc & 31;               // mt*64 ≡ 0 (mod 32)
      float sum = 0.f;
#pragma unroll
      for (int j = 0; j < 4; ++j) {
        float e = acc[i][j][r] + s1[(size_t)b * 512 + wn + 16 * j + mrow];
        sum += fast_tanh(e) * vv[j];
      }
      sum += __shfl_xor(sum, 1);
      sum += __shfl_xor(sum, 2);
      sum += __shfl_xor(sum, 4);
      sum += __shfl_xor(sum, 8);
      if (mrow == 0) part[w * 64 + mloc] = sum;
    }
  }
  __syncthreads();
  if (tid < 64) {
    float s = 0.f;
#pragma unroll
    for (int ww = 0; ww < 8; ++ww) s += part[ww * 64 + tid];
    int mg = mt * 64 + tid;            // global row m = s*32 + b
    score[(mg & 31) * SLEN + (mg >> 5)] = s;
  }
}

// ---- Masked softmax over s for each b; score stored b-major [32][2048] ----
__global__ __launch_bounds__(256) void softmax_k(const float* __restrict__ score,
                                                 const int* __restrict__ mask,
                                                 float* __restrict__ out) {
  int b = blockIdx.x;
  int tid = threadIdx.x;
  int lane = tid & 63, w = tid >> 6;
  __shared__ float red[8];
  float vals[8];
  float mx = -3.4e38f;
#pragma unroll
  for (int i = 0; i < 8; ++i) {
    int s = i * 256 + tid;
    float xv = score[b * SLEN + s];
    if (mask[b * SLEN + s] == 0) xv = -1e10f;
    vals[i] = xv;
    mx = fmaxf(mx, xv);
  }
#pragma unroll
  for (int off = 1; off < 64; off <<= 1) mx = fmaxf(mx, __shfl_xor(mx, off));
  if (lane == 0) red[w] = mx;
  __syncthreads();
  mx = fmaxf(fmaxf(red[0], red[1]), fmaxf(red[2], red[3]));
  float sum = 0.f;
#pragma unroll
  for (int i = 0; i < 8; ++i) {
    vals[i] = __expf(vals[i] - mx);
    sum += vals[i];
  }
#pragma unroll
  for (int off = 1; off < 64; off <<= 1) sum += __shfl_xor(sum, off);
  if (lane == 0) red[4 + w] = sum;
  __syncthreads();
  sum = red[4] + red[5] + red[6] + red[7];
  float inv = 1.0f / sum;
#pragma unroll
  for (int i = 0; i < 8; ++i) out[b * SLEN + i * 256 + tid] = vals[i] * inv;
}

extern "C" void kernel_launch(void* const* d_in, const int* in_sizes, int n_in,
                              void* d_out, int out_size, void* d_ws, size_t ws_size,
                              hipStream_t stream) {
  const float* hidden = (const float*)d_in[0];
  const float* eo     = (const float*)d_in[1];
  const int*   mask   = (const int*)d_in[2];
  const float* attn_w = (const float*)d_in[3];
  const float* attn_b = (const float*)d_in[4];
  const float* v      = (const float*)d_in[5];
  float* out = (float*)d_out;

  char* wsb = (char*)d_ws;
  _Float16* Bt = (_Float16*)wsb;                              // 1 MB
  float* s1    = (float*)(wsb + (1 << 20));                   // 64 KB
  float* score = (float*)(wsb + (1 << 20) + (1 << 16));       // 256 KB

  prep_k<<<4608, 256, 0, stream>>>(attn_w, attn_b, hidden, Bt, s1);
  gemm_k<<<1024, 512, 0, stream>>>(eo, Bt, s1, v, score);
  softmax_k<<<BATCH, 256, 0, stream>>>(score, mask, out);
}